// Round 6
// baseline (177.530 us; speedup 1.0000x reference)
//
#include <hip/hip_runtime.h>

// Problem: p1,p2 : (B=2, C=32, D=H=W=64) fp32. Pool 4x4x4 -> S=16.
// N = B*S^3 = 8192 rows of C=32. loss = ||A Aᵀ - B Bᵀ||_F² / N²
//           = (||AᵀA||² - 2||AᵀB||² + ||BᵀB||²) / N²  with 32x32 Grams only.
//
// v7: memset(48KB) + ONE fused kernel with last-block finalize.
// Wall model (r0-r5): pool time ~43-48us is pinned by HBM bandwidth shared
// with the harness's 268MB poison-fill writeback (65MB fetch + ~200MB wb
// at 6.3 TB/s ~= 42us) -- invariant to access pattern/ILP/occupancy. So:
// minimize OUR traffic (atomic 48KB Gram partials, not 6MB stores) and
// remove the finalize dispatch via device-scope done-counter + last-block
// reduction (no cooperative launch needed; r4 showed coop fails capture).

#define HW    4096      // 64*64
#define DHW   262144    // 64*64*64
#define NROW  8192
#define C     32
#define NPART 4         // spread Gram copies
#define NBLK  512

__global__ __launch_bounds__(1024) void fused_region_loss_kernel(
    const float* __restrict__ p1, const float* __restrict__ p2,
    float* __restrict__ G,       // [NPART][3072] zeroed by memset
    unsigned* __restrict__ cnt,  // done-counter, zeroed by memset
    float* __restrict__ out)
{
    const int bid = blockIdx.x;
    const int yo = bid & 15;
    const int zo = (bid >> 4) & 15;
    const int b  = bid >> 8;

    const int tid  = threadIdx.x;
    const int wv   = tid >> 6;       // 0..15
    const int lane = tid & 63;
    const int dy   = lane >> 4;      // 0..3
    const int x4   = lane & 15;      // 0..15 (float4 index along W)

    __shared__ float pa[C][17];      // +1 pad: conflict-free column reads
    __shared__ float pb[C][17];
    __shared__ float inva[16];
    __shared__ float invb[16];

    const size_t sp_off = (size_t)(4 * zo) * HW + (size_t)(4 * yo + dy) * 64 + 4 * x4;

    // ---- pool: wave wv loads channels {2wv,2wv+1} of both inputs;
    //      each wave-load is a contiguous 1KiB line
    float4 va[2][4], vb[2][4];
    #pragma unroll
    for (int cc = 0; cc < 2; ++cc) {
        const int c = wv * 2 + cc;
        const float* basea = p1 + (size_t)(b * C + c) * DHW + sp_off;
        const float* baseb = p2 + (size_t)(b * C + c) * DHW + sp_off;
        #pragma unroll
        for (int dz = 0; dz < 4; ++dz) {
            va[cc][dz] = *reinterpret_cast<const float4*>(basea + dz * HW);
            vb[cc][dz] = *reinterpret_cast<const float4*>(baseb + dz * HW);
        }
    }

    #pragma unroll
    for (int cc = 0; cc < 2; ++cc) {
        float sa = 0.f, sb = 0.f;
        #pragma unroll
        for (int dz = 0; dz < 4; ++dz) {
            sa += (va[cc][dz].x + va[cc][dz].y) + (va[cc][dz].z + va[cc][dz].w);
            sb += (vb[cc][dz].x + vb[cc][dz].y) + (vb[cc][dz].z + vb[cc][dz].w);
        }
        sa += __shfl_xor(sa, 16);  sa += __shfl_xor(sa, 32);
        sb += __shfl_xor(sb, 16);  sb += __shfl_xor(sb, 32);
        if (lane < 16) {
            pa[wv * 2 + cc][lane] = sa * (1.0f / 64.0f);
            pb[wv * 2 + cc][lane] = sb * (1.0f / 64.0f);
        }
    }
    __syncthreads();

    // ---- per-row inverse norms (rows = the 16 x-positions)
    if (tid < 32) {
        const int x = tid & 15;
        float ss = 0.f;
        if (tid < 16) {
            #pragma unroll
            for (int c2 = 0; c2 < C; ++c2) { const float v = pa[c2][x]; ss += v * v; }
            inva[x] = 1.0f / fmaxf(sqrtf(ss), 1e-8f);
        } else {
            #pragma unroll
            for (int c2 = 0; c2 < C; ++c2) { const float v = pb[c2][x]; ss += v * v; }
            invb[x] = 1.0f / fmaxf(sqrtf(ss), 1e-8f);
        }
    }
    __syncthreads();

    // ---- normalize in place
    {
        const int sel = tid >> 9;        // 0: pa, 1: pb
        const int c   = (tid >> 4) & 31;
        const int x   = tid & 15;
        if (sel == 0) pa[c][x] *= inva[x];
        else          pb[c][x] *= invb[x];
    }
    __syncthreads();

    // ---- Gram partials over this block's 16 rows: thread t owns (k,l)
    const int k = tid >> 5;              // 0..31
    const int l = tid & 31;              // 0..31
    float gaa = 0.f, gab = 0.f, gbb = 0.f;
    #pragma unroll
    for (int x = 0; x < 16; ++x) {
        const float ak = pa[k][x];       // same addr in half-wave: broadcast
        const float al = pa[l][x];       // stride-17: conflict-free
        const float bk = pb[k][x];
        const float bl = pb[l][x];
        gaa += ak * al;
        gab += ak * bl;
        gbb += bk * bl;
    }

    float* Gp = G + (size_t)(bid & (NPART - 1)) * 3072;
    atomicAdd(&Gp[       tid], gaa);     // tid == k*32+l ; device-scope
    atomicAdd(&Gp[1024 + tid], gab);
    atomicAdd(&Gp[2048 + tid], gbb);

    // ---- done-counter: release so our G-adds are visible before the count
    __syncthreads();
    __shared__ unsigned my_order;
    if (tid == 0) {
        __threadfence();   // device-scope release of this block's atomics
        my_order = __hip_atomic_fetch_add(cnt, 1u, __ATOMIC_ACQ_REL,
                                          __HIP_MEMORY_SCOPE_AGENT);
    }
    __syncthreads();
    if (my_order != NBLK - 1) return;

    // ================= last block: finalize =================
    __threadfence();   // acquire side
    {
        float s0 = 0.f, s1 = 0.f, s2 = 0.f;
        #pragma unroll
        for (int p = 0; p < NPART; ++p) {
            s0 += __hip_atomic_load(&G[p * 3072 +        tid], __ATOMIC_RELAXED,
                                    __HIP_MEMORY_SCOPE_AGENT);
            s1 += __hip_atomic_load(&G[p * 3072 + 1024 + tid], __ATOMIC_RELAXED,
                                    __HIP_MEMORY_SCOPE_AGENT);
            s2 += __hip_atomic_load(&G[p * 3072 + 2048 + tid], __ATOMIC_RELAXED,
                                    __HIP_MEMORY_SCOPE_AGENT);
        }
        float v = s0 * s0 + s2 * s2 - 2.f * s1 * s1;

        __shared__ float red[16];
        #pragma unroll
        for (int off = 32; off > 0; off >>= 1) v += __shfl_down(v, off);
        if ((tid & 63) == 0) red[tid >> 6] = v;
        __syncthreads();
        if (tid < 16) {
            float w = red[tid];
            #pragma unroll
            for (int off = 8; off > 0; off >>= 1) w += __shfl_down(w, off);
            if (tid == 0) out[0] = w / ((float)NROW * (float)NROW);
        }
    }
}

extern "C" void kernel_launch(void* const* d_in, const int* in_sizes, int n_in,
                              void* d_out, int out_size, void* d_ws, size_t ws_size,
                              hipStream_t stream) {
    const float* p1 = (const float*)d_in[0];
    const float* p2 = (const float*)d_in[1];
    float* out = (float*)d_out;

    float* G      = (float*)d_ws;                 // NPART*3072 floats = 48 KiB
    unsigned* cnt = (unsigned*)((char*)d_ws + NPART * 3072 * sizeof(float));

    // zero Gram partials + done-counter (one small fill)
    hipMemsetAsync(d_ws, 0, NPART * 3072 * sizeof(float) + 64, stream);

    fused_region_loss_kernel<<<NBLK, 1024, 0, stream>>>(p1, p2, G, cnt, out);
}

// Round 7
// 149.913 us; speedup vs baseline: 1.1842x; 1.1842x over previous
//
#include <hip/hip_runtime.h>

// Problem: p1,p2 : (B=2, C=32, D=H=W=64) fp32. Pool 4x4x4 -> S=16.
// N = B*S^3 = 8192 rows of C=32. loss = ||A Aᵀ - B Bᵀ||_F² / N²
//           = (||AᵀA||² - 2||AᵀB||² + ||BᵀB||²) / N²  with 32x32 Grams only.
//
// v8 = v3 (round-2 config, best verified: 151.3 us). Reverts round 6's
// last-block-done pattern (+32 us structural cost from threadfence/acq-rel
// tail: warm-cache replays still took 83us) and round 5's plain-store
// partials (+12.6 MB traffic for ~0 dispatch-gap gain: launches are
// graph-captured, boundaries cost ~1-2 us, not 10).
// Structure: memset(192KB) + fused pool/norm/gram (atomicAdd into NPART=16
// spread copies) + 1-block finalize.
// Pool phase (43-47us) is invariant across 6 structural variants
// (scatter/stream, occupancy 26-63%, forced ILP, block size): treated as
// the service-rate wall for this 134MB working set under harness traffic.

#define HW    4096      // 64*64
#define DHW   262144    // 64*64*64
#define NROW  8192
#define C     32
#define NPART 16        // partial Gram copies (atomic-contention spreading)

// ---------------------------------------------------------------------------
// Fused pool + normalize + Gram partials.
// grid = 512 : (b,zo,yo). 1024 threads = 16 waves.
// Wave wv handles channels {2wv, 2wv+1} of BOTH inputs.
// Lane = dy*16 + x4 : each wave-load is one contiguous 1KiB line.
// ---------------------------------------------------------------------------
__global__ __launch_bounds__(1024) void fused_pool_gram_kernel(
    const float* __restrict__ p1, const float* __restrict__ p2,
    float* __restrict__ G)
{
    const int bid = blockIdx.x;
    const int yo = bid & 15;
    const int zo = (bid >> 4) & 15;
    const int b  = bid >> 8;

    const int tid  = threadIdx.x;
    const int wv   = tid >> 6;       // 0..15
    const int lane = tid & 63;
    const int dy   = lane >> 4;      // 0..3
    const int x4   = lane & 15;      // 0..15 (float4 index along W)

    __shared__ float pa[C][17];      // +1 pad: conflict-free column reads
    __shared__ float pb[C][17];
    __shared__ float inva[16];
    __shared__ float invb[16];

    const size_t sp_off = (size_t)(4 * zo) * HW + (size_t)(4 * yo + dy) * 64 + 4 * x4;

    float4 va[2][4], vb[2][4];
    #pragma unroll
    for (int cc = 0; cc < 2; ++cc) {
        const int c = wv * 2 + cc;
        const float* basea = p1 + (size_t)(b * C + c) * DHW + sp_off;
        const float* baseb = p2 + (size_t)(b * C + c) * DHW + sp_off;
        #pragma unroll
        for (int dz = 0; dz < 4; ++dz) {
            va[cc][dz] = *reinterpret_cast<const float4*>(basea + dz * HW);
            vb[cc][dz] = *reinterpret_cast<const float4*>(baseb + dz * HW);
        }
    }

    #pragma unroll
    for (int cc = 0; cc < 2; ++cc) {
        float sa = 0.f, sb = 0.f;
        #pragma unroll
        for (int dz = 0; dz < 4; ++dz) {
            sa += (va[cc][dz].x + va[cc][dz].y) + (va[cc][dz].z + va[cc][dz].w);
            sb += (vb[cc][dz].x + vb[cc][dz].y) + (vb[cc][dz].z + vb[cc][dz].w);
        }
        sa += __shfl_xor(sa, 16);  sa += __shfl_xor(sa, 32);
        sb += __shfl_xor(sb, 16);  sb += __shfl_xor(sb, 32);
        if (lane < 16) {
            pa[wv * 2 + cc][lane] = sa * (1.0f / 64.0f);
            pb[wv * 2 + cc][lane] = sb * (1.0f / 64.0f);
        }
    }
    __syncthreads();

    // per-row inverse norms (rows are the 16 x-positions)
    if (tid < 32) {
        const int x = tid & 15;
        float ss = 0.f;
        if (tid < 16) {
            #pragma unroll
            for (int c2 = 0; c2 < C; ++c2) { const float v = pa[c2][x]; ss += v * v; }
            inva[x] = 1.0f / fmaxf(sqrtf(ss), 1e-8f);
        } else {
            #pragma unroll
            for (int c2 = 0; c2 < C; ++c2) { const float v = pb[c2][x]; ss += v * v; }
            invb[x] = 1.0f / fmaxf(sqrtf(ss), 1e-8f);
        }
    }
    __syncthreads();

    // normalize in place (1024 threads cover 2 x 32 x 16 entries)
    {
        const int sel = tid >> 9;        // 0: pa, 1: pb
        const int c   = (tid >> 4) & 31;
        const int x   = tid & 15;
        if (sel == 0) pa[c][x] *= inva[x];
        else          pb[c][x] *= invb[x];
    }
    __syncthreads();

    // Gram partials over this block's 16 rows: thread t owns (k,l)
    const int k = tid >> 5;              // 0..31
    const int l = tid & 31;              // 0..31
    float gaa = 0.f, gab = 0.f, gbb = 0.f;
    #pragma unroll
    for (int x = 0; x < 16; ++x) {
        const float ak = pa[k][x];       // same addr in half-wave: broadcast
        const float al = pa[l][x];       // stride-17: conflict-free
        const float bk = pb[k][x];
        const float bl = pb[l][x];
        gaa += ak * al;
        gab += ak * bl;
        gbb += bk * bl;
    }

    float* Gp = G + (size_t)(bid & (NPART - 1)) * 3072;
    atomicAdd(&Gp[       k * 32 + l], gaa);
    atomicAdd(&Gp[1024 + k * 32 + l], gab);
    atomicAdd(&Gp[2048 + k * 32 + l], gbb);
}

// ---------------------------------------------------------------------------
// Finalize: loss = (sum Gaa² - 2 sum Gab² + sum Gbb²) / N²  (sum NPART parts
// per entry BEFORE squaring).
// ---------------------------------------------------------------------------
__global__ __launch_bounds__(1024) void finalize_kernel(
    const float* __restrict__ G, float* __restrict__ out)
{
    const int t = threadIdx.x;
    float gaa = 0.f, gab = 0.f, gbb = 0.f;
    #pragma unroll
    for (int p = 0; p < NPART; ++p) {
        gaa += G[p * 3072 + t];
        gab += G[p * 3072 + 1024 + t];
        gbb += G[p * 3072 + 2048 + t];
    }
    float v = gaa * gaa + gbb * gbb - 2.f * gab * gab;

    __shared__ float red[16];
    #pragma unroll
    for (int off = 32; off > 0; off >>= 1) v += __shfl_down(v, off);
    if ((t & 63) == 0) red[t >> 6] = v;
    __syncthreads();
    if (t < 16) {
        float w = red[t];
        #pragma unroll
        for (int off = 8; off > 0; off >>= 1) w += __shfl_down(w, off);
        if (t == 0) out[0] = w / ((float)NROW * (float)NROW);
    }
}

extern "C" void kernel_launch(void* const* d_in, const int* in_sizes, int n_in,
                              void* d_out, int out_size, void* d_ws, size_t ws_size,
                              hipStream_t stream) {
    const float* p1 = (const float*)d_in[0];
    const float* p2 = (const float*)d_in[1];
    float* out = (float*)d_out;

    float* G = (float*)d_ws;   // NPART * 3072 floats = 192 KiB

    hipMemsetAsync(G, 0, NPART * 3072 * sizeof(float), stream);

    fused_pool_gram_kernel<<<512, 1024, 0, stream>>>(p1, p2, G);
    finalize_kernel<<<1, 1024, 0, stream>>>(G, out);
}